// Round 15
// baseline (195.389 us; speedup 1.0000x reference)
//
#include <hip/hip_runtime.h>
#include <hip/hip_bf16.h>

#define S_LEN 4096
#define DM    512
#define NH    8
#define DK    64

typedef __attribute__((ext_vector_type(8))) __bf16 bf16x8;
typedef __attribute__((ext_vector_type(4))) float  f32x4;
typedef unsigned short u16;
typedef unsigned int   u32;
typedef unsigned long long u64;

// Q-GEMM epilogue scale: 1/sqrt(64) * log2(e)  (softmax in log2 domain)
#define SQ_SCALE (0.125f * 1.44269504f)
// Fixed softmax shift (log2-domain). Shift-invariant; l-division restores scale.
#define FMAX 12.0f

// Split-K over the key axis: 4 partials of 1024 keys each.
#define NPART 4
#define KSPAN 1024

__device__ __forceinline__ u16 f2bf(float f) {
  union { float f; u32 i; } v; v.f = f;
  u32 r = v.i + 0x7fff + ((v.i >> 16) & 1);   // RNE
  return (u16)(r >> 16);
}
__device__ __forceinline__ float bf2f(u16 u) {
  union { u32 i; float f; } v; v.i = ((u32)u) << 16; return v.f;
}

// pack two f32 -> one u32 of 2 bf16 (RNE), single instruction; lo16=a, hi16=b.
// Verified correct in R8/R14.
__device__ __forceinline__ u32 cvtpk(float a, float b) {
  u32 r;
  asm("v_cvt_pk_bf16_f32 %0, %1, %2" : "=v"(r) : "v"(a), "v"(b));
  return r;
}

// async global->LDS DMA, 16B per lane (dest: wave-uniform base + lane*16)
__device__ __forceinline__ void gl_lds16(const u16* g, u16* l) {
  __builtin_amdgcn_global_load_lds(
      (const __attribute__((address_space(1))) u32*)g,
      (__attribute__((address_space(3))) u32*)l, 16, 0, 0);
}

// ---------------------------------------------------------------------------
// prep: fused mask-pack + fp32->bf16 conversion (unchanged from R14-verified).
__global__ __launch_bounds__(256) void prep(
    const int* __restrict__ mask, const float* __restrict__ x,
    const float* __restrict__ wq, const float* __restrict__ wk,
    const float* __restrict__ wv, const float* __restrict__ dw,
    u64* __restrict__ mb, u16* __restrict__ xb, u16* __restrict__ wcat,
    u16* __restrict__ dwb) {
  const int b = blockIdx.x, t = threadIdx.x;
  if (b < 8192) {
    const int lane = t & 63, w4 = t >> 6;
    const int wb = b * 32 + w4 * 8;
    u64 bw[8];
#pragma unroll
    for (int j = 0; j < 8; j++)
      bw[j] = __ballot(mask[(size_t)(wb + j) * 64 + lane] != 0);
    if (lane == 0) {
#pragma unroll
      for (int j = 0; j < 8; j++) mb[wb + j] = bw[j];
    }
  } else {
    const int c = b - 8192;
    const float* src; u16* dst; size_t off;
    if      (c < 2048) { src = x;  dst = xb;   off = (size_t)c * 1024; }
    else if (c < 2304) { src = wq; dst = wcat; off = (size_t)(c - 2048) * 1024; }
    else if (c < 2560) { src = wk; dst = wcat + 262144; off = (size_t)(c - 2304) * 1024; }
    else if (c < 2816) { src = wv; dst = wcat + 524288; off = (size_t)(c - 2560) * 1024; }
    else               { src = dw; dst = dwb;  off = (size_t)(c - 2816) * 1024; }
    size_t i = off + (size_t)t * 4;
    float4 v = *reinterpret_cast<const float4*>(src + i);
    ushort4 o = make_ushort4(f2bf(v.x), f2bf(v.y), f2bf(v.z), f2bf(v.w));
    *reinterpret_cast<ushort4*>(dst + i) = o;
  }
}

// ---------------------------------------------------------------------------
// Fused QKV projection, 64(m) x 128(n) tiles: C[4096,1536] = x @ Wcat^T + bias.
// grid (12, 64). seg 0=Q (scaled), 1=K, 2=V.  (unchanged from R7/R14-verified)
// V output layout V4[(h*64+d)][tile*64 + slot] (see attn_mfma).
__global__ __launch_bounds__(256) void qkv_gemm(
    const u16* __restrict__ A, const u16* __restrict__ Wcat,
    const float* __restrict__ bq, const float* __restrict__ bk,
    const float* __restrict__ bv,
    u16* __restrict__ Qb, u16* __restrict__ Kb, u16* __restrict__ V4) {
  __shared__ u16 As[2][64 * 64];    // 16 KB
  __shared__ u16 Ws[2][128 * 64];   // 32 KB (region reused as T in V epilogue)
  const int t = threadIdx.x;
  const int lane = t & 63, wv = t >> 6;
  const int m16 = lane & 15, quad = lane >> 4;
  const int n0g = blockIdx.x * 128, m0 = blockIdx.y * 64;
  const int seg = n0g >> 9;
  const int n0 = n0g & 511;
  const int mq = wv >> 1, nq = wv & 1;   // wave quadrant

  const u16* asrc[2]; int ldsoA[2];
#pragma unroll
  for (int c0 = 0; c0 < 2; c0++) {
    int c = t + c0 * 256;
    int row = c >> 3, swc = ((c & 7) ^ (row & 7)) * 8;
    asrc[c0] = A + (size_t)(m0 + row) * DM + swc;
    ldsoA[c0] = c * 8;
  }
  const u16* wsrc[4]; int ldsoW[4];
#pragma unroll
  for (int c0 = 0; c0 < 4; c0++) {
    int c = t + c0 * 256;
    int row = c >> 3, swc = ((c & 7) ^ (row & 7)) * 8;
    wsrc[c0] = Wcat + (size_t)(n0g + row) * DM + swc;
    ldsoW[c0] = c * 8;
  }

  f32x4 acc[2][4];
#pragma unroll
  for (int i = 0; i < 2; i++)
#pragma unroll
    for (int j = 0; j < 4; j++) acc[i][j] = (f32x4)0.f;

#pragma unroll
  for (int c0 = 0; c0 < 2; c0++) gl_lds16(asrc[c0], &As[0][ldsoA[c0]]);
#pragma unroll
  for (int c0 = 0; c0 < 4; c0++) gl_lds16(wsrc[c0], &Ws[0][ldsoW[c0]]);
  __syncthreads();

  const int xorv = m16 & 7;   // read-side granule swizzle
  int cur = 0;
  for (int k0 = 0; k0 < DM; k0 += 64) {
    if (k0 + 64 < DM) {
#pragma unroll
      for (int c0 = 0; c0 < 2; c0++)
        gl_lds16(asrc[c0] + k0 + 64, &As[cur ^ 1][ldsoA[c0]]);
#pragma unroll
      for (int c0 = 0; c0 < 4; c0++)
        gl_lds16(wsrc[c0] + k0 + 64, &Ws[cur ^ 1][ldsoW[c0]]);
    }
    const u16* Ac = As[cur];
    const u16* Wc = Ws[cur];
#pragma unroll
    for (int kk = 0; kk < 64; kk += 32) {
      const int gcol = (((quad + (kk >> 3)) ^ xorv) * 8);
      bf16x8 a0 = *reinterpret_cast<const bf16x8*>(&Ac[(mq * 32 + m16) * 64 + gcol]);
      bf16x8 a1 = *reinterpret_cast<const bf16x8*>(&Ac[(mq * 32 + 16 + m16) * 64 + gcol]);
#pragma unroll
      for (int ct = 0; ct < 4; ct++) {
        bf16x8 b = *reinterpret_cast<const bf16x8*>(&Wc[(nq * 64 + ct * 16 + m16) * 64 + gcol]);
        acc[0][ct] = __builtin_amdgcn_mfma_f32_16x16x32_bf16(a0, b, acc[0][ct], 0, 0, 0);
        acc[1][ct] = __builtin_amdgcn_mfma_f32_16x16x32_bf16(a1, b, acc[1][ct], 0, 0, 0);
      }
    }
    __syncthreads();
    cur ^= 1;
  }

  const float* bias = (seg == 0) ? bq : (seg == 1) ? bk : bv;
  const float scale = (seg == 0) ? SQ_SCALE : 1.f;
  float bn[4];
#pragma unroll
  for (int ct = 0; ct < 4; ct++) bn[ct] = bias[n0 + nq * 64 + ct * 16 + m16];

  if (seg == 2) {
    u16* T = &Ws[0][0];   // 9216 u16 needed <= 16384 available
#pragma unroll
    for (int rt = 0; rt < 2; rt++)
#pragma unroll
      for (int ct = 0; ct < 4; ct++)
#pragma unroll
        for (int r = 0; r < 4; r++)
          T[(nq * 64 + ct * 16 + m16) * 72 + mq * 32 + rt * 16 + quad * 4 + r] =
              f2bf(acc[rt][ct][r] + bn[ct]);
    __syncthreads();
    const int h    = m0 >> 9;
    const int mp   = m0 & 511;
    const int cseg = n0 >> 7;
#pragma unroll
    for (int c0 = 0; c0 < 4; c0++) {
      int c = t + c0 * 256;
      int d  = c >> 4;
      int tl = (c >> 1) & 7;
      int cl = c & 1;
      uint4 v = *reinterpret_cast<const uint4*>(&T[(cl * 64 + d) * 72 + tl * 8]);
      *reinterpret_cast<uint4*>(
          &V4[(size_t)(h * 64 + d) * 4096 + ((mp >> 3) + tl) * 64 + cl * 32 + cseg * 8]) = v;
    }
  } else {
    u16* dst = (seg == 0) ? Qb : Kb;
#pragma unroll
    for (int rt = 0; rt < 2; rt++)
#pragma unroll
      for (int ct = 0; ct < 4; ct++) {
        int n = n0 + nq * 64 + ct * 16 + m16;
#pragma unroll
        for (int r = 0; r < 4; r++) {
          int m = m0 + mq * 32 + rt * 16 + quad * 4 + r;
          dst[(size_t)m * DM + n] = f2bf((acc[rt][ct][r] + bn[ct]) * scale);
        }
      }
  }
}

// ---------------------------------------------------------------------------
// Dense out-proj, R15: m-tile 64 -> 32 for occupancy. grid (8, 128) = 1024
// blocks = 4 blocks/CU (was 512 = 2/CU); LDS 24 KB. Wave quadrant 2x2:
// rows mq*16, cols nq*32, acc[2]. Staging/swizzle arithmetic unchanged
// (row offsets are multiples of 16/32 so row&7 == m16&7 involution holds).
// C[4096,512](f32) = A @ dw^T + db.
__global__ __launch_bounds__(256) void dense_gemm(
    const u16* __restrict__ A, const u16* __restrict__ W,
    const float* __restrict__ bias, float* __restrict__ Cout) {
  __shared__ u16 As[2][32 * 64];   // 4 KB each
  __shared__ u16 Ws[2][64 * 64];   // 8 KB each
  const int t = threadIdx.x;
  const int lane = t & 63, wv = t >> 6;
  const int m16 = lane & 15, quad = lane >> 4;
  const int n0 = blockIdx.x * 64, m0 = blockIdx.y * 32;
  const int mq = wv >> 1, nq = wv & 1;   // wave quadrant

  // A: 32x64 = 256 chunks (1/thread). W: 64x64 = 512 chunks (2/thread).
  const u16* asrc; int ldsoA;
  {
    int c = t;
    int row = c >> 3, swc = ((c & 7) ^ (row & 7)) * 8;
    asrc = A + (size_t)(m0 + row) * DM + swc;
    ldsoA = c * 8;
  }
  const u16* wsrc[2]; int ldsoW[2];
#pragma unroll
  for (int c0 = 0; c0 < 2; c0++) {
    int c = t + c0 * 256;
    int row = c >> 3, swc = ((c & 7) ^ (row & 7)) * 8;
    wsrc[c0] = W + (size_t)(n0 + row) * DM + swc;
    ldsoW[c0] = c * 8;
  }

  f32x4 acc[2];
#pragma unroll
  for (int j = 0; j < 2; j++) acc[j] = (f32x4)0.f;

  gl_lds16(asrc, &As[0][ldsoA]);
#pragma unroll
  for (int c0 = 0; c0 < 2; c0++) gl_lds16(wsrc[c0], &Ws[0][ldsoW[c0]]);
  __syncthreads();

  const int xorv = m16 & 7;
  int cur = 0;
  for (int k0 = 0; k0 < DM; k0 += 64) {
    if (k0 + 64 < DM) {
      gl_lds16(asrc + k0 + 64, &As[cur ^ 1][ldsoA]);
#pragma unroll
      for (int c0 = 0; c0 < 2; c0++)
        gl_lds16(wsrc[c0] + k0 + 64, &Ws[cur ^ 1][ldsoW[c0]]);
    }
    const u16* Ac = As[cur];
    const u16* Wc = Ws[cur];
#pragma unroll
    for (int kk = 0; kk < 64; kk += 32) {
      const int gcol = (((quad + (kk >> 3)) ^ xorv) * 8);
      bf16x8 a = *reinterpret_cast<const bf16x8*>(&Ac[(mq * 16 + m16) * 64 + gcol]);
#pragma unroll
      for (int ct = 0; ct < 2; ct++) {
        bf16x8 b = *reinterpret_cast<const bf16x8*>(&Wc[(nq * 32 + ct * 16 + m16) * 64 + gcol]);
        acc[ct] = __builtin_amdgcn_mfma_f32_16x16x32_bf16(a, b, acc[ct], 0, 0, 0);
      }
    }
    __syncthreads();
    cur ^= 1;
  }

  float bn[2];
#pragma unroll
  for (int ct = 0; ct < 2; ct++) bn[ct] = bias[n0 + nq * 32 + ct * 16 + m16];
#pragma unroll
  for (int ct = 0; ct < 2; ct++) {
    int n = n0 + nq * 32 + ct * 16 + m16;
#pragma unroll
    for (int r = 0; r < 4; r++) {
      int m = m0 + mq * 16 + quad * 4 + r;
      Cout[(size_t)m * DM + n] = acc[ct][r] + bn[ct];
    }
  }
}

// ---------------------------------------------------------------------------
// exp2 + mask + pack one q-subtile's scores into the two PV A-fragments.
// Mask bit for C slot (ct,r): true key = 32(ct&1) + 16(r>>1) + 8(r&1)
// + 2*quad + (ct>>1); lo/hi are the lane's mask word pre-shifted by 2*quad.
// cvt_pk packing (R14-verified).
__device__ __forceinline__ void pack_p(const f32x4* s, u32 lo, u32 hi,
                                       uint4& o0, uint4& o1) {
  u32 pk[8];
#pragma unroll
  for (int ct = 0; ct < 4; ct++) {
    u32 w = (ct & 1) ? hi : lo;
    int b = ct >> 1;
    float p0 = __builtin_amdgcn_exp2f(((w >> b) & 1u)        ? -1e9f : s[ct][0]);
    float p1 = __builtin_amdgcn_exp2f(((w >> (b + 8)) & 1u)  ? -1e9f : s[ct][1]);
    float p2 = __builtin_amdgcn_exp2f(((w >> (b + 16)) & 1u) ? -1e9f : s[ct][2]);
    float p3 = __builtin_amdgcn_exp2f(((w >> (b + 24)) & 1u) ? -1e9f : s[ct][3]);
    pk[2 * ct]     = cvtpk(p0, p1);
    pk[2 * ct + 1] = cvtpk(p2, p3);
  }
  o0 = make_uint4(pk[0], pk[1], pk[2], pk[3]);
  o1 = make_uint4(pk[4], pk[5], pk[6], pk[7]);
}

// ---------------------------------------------------------------------------
// Flash attention v6 (R14-verified, 57.8 us): LDS double-buffer filled by
// global_load_lds DMA, 1 barrier/iter, sigma^{-1}-pre-permuted K source rows,
// bank-XOR involution (0 conflicts). S^T C-layout registers exp2'd +
// cvt_pk-packed ARE the PV A-fragments. Grid 1D 1024, lin&7 = (h,g) group.
__global__ __launch_bounds__(256, 4) void attn_mfma(
    const u16* __restrict__ Q, const u16* __restrict__ K,
    const u16* __restrict__ V4, const u64* __restrict__ mbits,
    u16* __restrict__ Op, float* __restrict__ Lp) {
  __shared__ u16 Ks[2][64 * 64];   // 8 KB each
  __shared__ u16 Vs[2][64 * 64];

  const int t = threadIdx.x;
  const int lane = t & 63, w4 = t >> 6;
  const int m16 = lane & 15, quad = lane >> 4;
  const int lin = blockIdx.x;
  const int q0 = ((lin >> 3) & 31) * 128;
  const int hg = ((lin >> 8) << 3) | (lin & 7);   // 0..31, lin&7 = XCD group
  const int h = hg & 7;
  const int g = hg >> 3;                          // key quarter: 1024 keys
  const size_t hoff = (size_t)h * S_LEN * DK;
  const size_t kbase = hoff + (size_t)g * KSPAN * DK;

  // Q fragments for the wave's two q-subtiles (pre-scaled in Q-GEMM)
  const u16* qpA = Q + hoff + (size_t)(q0 + w4 * 32 + m16) * DK + quad * 8;
  bf16x8 qloA = *reinterpret_cast<const bf16x8*>(qpA);
  bf16x8 qhiA = *reinterpret_cast<const bf16x8*>(qpA + 32);
  bf16x8 qloB = *reinterpret_cast<const bf16x8*>(qpA + 16 * DK);
  bf16x8 qhiB = *reinterpret_cast<const bf16x8*>(qpA + 16 * DK + 32);

  union { u16 u[8]; bf16x8 v; } onesu;
#pragma unroll
  for (int j = 0; j < 8; j++) onesu.u[j] = 0x3F80;
  const bf16x8 ones = onesu.v;

  // DMA staging geometry (thread-constant); see R6 comments.
  const int l = lane;
  const int colu = ((l & 7) ^ (l >> 3)) * 8;      // u16 units
  const u16* kp[2]; const u16* vp[2]; int ldso[2];
#pragma unroll
  for (int i = 0; i < 2; i++) {
    int row = (w4 * 2 + i) * 8 + (l >> 3);
    int inv = (((row >> 4) & 1) << 5) | (((row >> 1) & 1) << 4) | ((row & 1) << 3) |
              (((row >> 3) & 1) << 2) | (((row >> 2) & 1) << 1) | ((row >> 5) & 1);
    kp[i] = K + kbase + (size_t)inv * DK + colu;
    vp[i] = V4 + (size_t)(h * 64 + row) * 4096 + g * KSPAN + colu;
    ldso[i] = (w4 * 2 + i) * 512 + l * 8;        // u16 units, 16B/lane
  }

  const u64* mpA = &mbits[(size_t)(q0 + w4 * 32 + m16) * 64 + ((g * KSPAN) >> 6)];
  const u64* mpB = mpA + (size_t)16 * 64;   // +16 q rows

  f32x4 accA[4], accB[4];
  f32x4 acc_lA = (f32x4)0.f, acc_lB = (f32x4)0.f;
#pragma unroll
  for (int dt = 0; dt < 4; dt++) { accA[dt] = (f32x4)0.f; accB[dt] = (f32x4)0.f; }

  // Prologue: DMA tile 0 into buf 0; mask words for tile 0 into regs.
#pragma unroll
  for (int i = 0; i < 2; i++) {
    gl_lds16(kp[i], &Ks[0][ldso[i]]);
    gl_lds16(vp[i], &Vs[0][ldso[i]]);
  }
  u64 rmA = mpA[0], rmB = mpB[0];
  __syncthreads();   // drains tile-0 DMA

  const int xorv = (m16 & 7) * 8;   // read-side swizzle (u16 units)
  int cur = 0;
#pragma unroll 1
  for (int k0 = 0; k0 < KSPAN; k0 += 64) {
    // Issue next tile's DMA first: latency hides under this tile's compute.
    if (k0 + 64 < KSPAN) {
#pragma unroll
      for (int i = 0; i < 2; i++) {
        gl_lds16(kp[i] + (size_t)(k0 + 64) * DK, &Ks[cur ^ 1][ldso[i]]);
        gl_lds16(vp[i] + (k0 + 64),              &Vs[cur ^ 1][ldso[i]]);
      }
    }
    u64 mqA = rmA >> (2 * quad);
    u64 mqB = rmB >> (2 * quad);
    if (k0 + 64 < KSPAN) { rmA = mpA[(k0 >> 6) + 1]; rmB = mpB[(k0 >> 6) + 1]; }

    const u16* Kc = Ks[cur];
    const u16* Vc = Vs[cur];

    // S^T - FMAX for both q-subtiles; each K fragment feeds 2 MFMAs
    f32x4 sA[4], sB[4];
#pragma unroll
    for (int ct = 0; ct < 4; ct++) { sA[ct] = (f32x4)(-FMAX); sB[ct] = (f32x4)(-FMAX); }
#pragma unroll
    for (int ct = 0; ct < 4; ct++) {
      const int rb = (ct * 16 + m16) * 64;
      bf16x8 klo = *reinterpret_cast<const bf16x8*>(&Kc[rb + ((quad * 8) ^ xorv)]);
      bf16x8 khi = *reinterpret_cast<const bf16x8*>(&Kc[rb + ((quad * 8 + 32) ^ xorv)]);
      sA[ct] = __builtin_amdgcn_mfma_f32_16x16x32_bf16(klo, qloA, sA[ct], 0, 0, 0);
      sA[ct] = __builtin_amdgcn_mfma_f32_16x16x32_bf16(khi, qhiA, sA[ct], 0, 0, 0);
      sB[ct] = __builtin_amdgcn_mfma_f32_16x16x32_bf16(klo, qloB, sB[ct], 0, 0, 0);
      sB[ct] = __builtin_amdgcn_mfma_f32_16x16x32_bf16(khi, qhiB, sB[ct], 0, 0, 0);
    }

    // exp2 + pack: registers become the PV A-fragments directly (no LDS)
    union { uint4 i; bf16x8 v; } pA0, pA1, pB0, pB1;
    pack_p(sA, (u32)mqA, (u32)(mqA >> 32), pA0.i, pA1.i);
    pack_p(sB, (u32)mqB, (u32)(mqB >> 32), pB0.i, pB1.i);

    // O += P @ V ; l += P @ 1; each V fragment feeds 2 MFMAs
#pragma unroll
    for (int dt = 0; dt < 4; dt++) {
      const int rb = (dt * 16 + m16) * 64;
      bf16x8 vlo = *reinterpret_cast<const bf16x8*>(&Vc[rb + ((quad * 8) ^ xorv)]);
      bf16x8 vhi = *reinterpret_cast<const bf16x8*>(&Vc[rb + ((quad * 8 + 32) ^ xorv)]);
      accA[dt] = __builtin_amdgcn_mfma_f32_16x16x32_bf16(pA0.v, vlo, accA[dt], 0, 0, 0);
      accA[dt] = __builtin_amdgcn_mfma_f32_16x16x32_bf16(pA1.v, vhi, accA[dt], 0, 0, 0);
      accB[dt] = __builtin_amdgcn_mfma_f32_16x16x32_bf16(pB0.v, vlo, accB[dt], 0, 0, 0);
      accB[dt] = __builtin_amdgcn_mfma_f32_16x16x32_bf16(pB1.v, vhi, accB[dt], 0, 0, 0);
    }
    acc_lA = __builtin_amdgcn_mfma_f32_16x16x32_bf16(pA0.v, ones, acc_lA, 0, 0, 0);
    acc_lA = __builtin_amdgcn_mfma_f32_16x16x32_bf16(pA1.v, ones, acc_lA, 0, 0, 0);
    acc_lB = __builtin_amdgcn_mfma_f32_16x16x32_bf16(pB0.v, ones, acc_lB, 0, 0, 0);
    acc_lB = __builtin_amdgcn_mfma_f32_16x16x32_bf16(pB1.v, ones, acc_lB, 0, 0, 0);

    __syncthreads();   // sync + drain next-tile DMA (hidden under compute)
    cur ^= 1;
  }

  // partial O (unnormalized bf16) + partial l (f32)
  u16* Og = Op + (size_t)g * 2097152;
#pragma unroll
  for (int dt = 0; dt < 4; dt++)
#pragma unroll
    for (int r = 0; r < 4; r++) {
      Og[(size_t)(q0 + w4 * 32 + quad * 4 + r) * DM + h * DK + dt * 16 + m16] =
          f2bf(accA[dt][r]);
      Og[(size_t)(q0 + w4 * 32 + 16 + quad * 4 + r) * DM + h * DK + dt * 16 + m16] =
          f2bf(accB[dt][r]);
    }
  if (m16 == 0) {
#pragma unroll
    for (int r = 0; r < 4; r++) {
      Lp[g * 32768 + h * 4096 + q0 + w4 * 32 + quad * 4 + r] = acc_lA[r];
      Lp[g * 32768 + h * 4096 + q0 + w4 * 32 + 16 + quad * 4 + r] = acc_lB[r];
    }
  }
}

// ---------------------------------------------------------------------------
// Merge the four key-quarter partials: Out = sum(O_g) / sum(l_g). bf16 out.
__global__ __launch_bounds__(256) void attn_merge(
    const u16* __restrict__ Op, const float* __restrict__ Lp,
    u16* __restrict__ Out) {
  int i8 = (blockIdx.x * 256 + threadIdx.x) * 8;   // 8 elems/thread, same (q,h)
  int q = i8 >> 9;
  int h = (i8 >> 6) & 7;
  float l = 0.f;
#pragma unroll
  for (int part = 0; part < NPART; part++) l += Lp[part * 32768 + h * 4096 + q];
  float rl = 1.f / l;
  float o[8];
#pragma unroll
  for (int j = 0; j < 8; j++) o[j] = 0.f;
#pragma unroll
  for (int part = 0; part < NPART; part++) {
    ushort4 v0 = *reinterpret_cast<const ushort4*>(Op + (size_t)part * 2097152 + i8);
    ushort4 v1 = *reinterpret_cast<const ushort4*>(Op + (size_t)part * 2097152 + i8 + 4);
    o[0] += bf2f(v0.x); o[1] += bf2f(v0.y); o[2] += bf2f(v0.z); o[3] += bf2f(v0.w);
    o[4] += bf2f(v1.x); o[5] += bf2f(v1.y); o[6] += bf2f(v1.z); o[7] += bf2f(v1.w);
  }
  ushort4 o0 = make_ushort4(f2bf(o[0] * rl), f2bf(o[1] * rl),
                            f2bf(o[2] * rl), f2bf(o[3] * rl));
  ushort4 o1 = make_ushort4(f2bf(o[4] * rl), f2bf(o[5] * rl),
                            f2bf(o[6] * rl), f2bf(o[7] * rl));
  *reinterpret_cast<ushort4*>(Out + i8) = o0;
  *reinterpret_cast<ushort4*>(Out + i8 + 4) = o1;
}

// ---------------------------------------------------------------------------
extern "C" void kernel_launch(void* const* d_in, const int* in_sizes, int n_in,
                              void* d_out, int out_size, void* d_ws, size_t ws_size,
                              hipStream_t stream) {
  const float* x    = (const float*)d_in[0];
  const int*   mask = (const int*)d_in[1];
  const float* wq_w = (const float*)d_in[2];
  const float* wq_b = (const float*)d_in[3];
  const float* wk_w = (const float*)d_in[4];
  const float* wk_b = (const float*)d_in[5];
  const float* wv_w = (const float*)d_in[6];
  const float* wv_b = (const float*)d_in[7];
  const float* dw   = (const float*)d_in[8];
  const float* db   = (const float*)d_in[9];

  // ws (u16 elems): xb 2M | wcat 768K | dwb 256K | Qb/Kb/V4 2M each |
  // Opart 4x2M | mb 256K u64 | Lp 128K f32.  ~37 MB total.
  u16* xb    = (u16*)d_ws;
  u16* wcat  = xb    + 2097152;
  u16* dwb   = wcat  + 786432;
  u16* Qb    = dwb   + 262144;
  u16* Kb    = Qb    + 2097152;
  u16* V4    = Kb    + 2097152;
  u16* Opart = V4    + 2097152;
  u64* mb    = (u64*)(Opart + (size_t)NPART * 2097152);
  float* Lp  = (float*)(mb + 262144);

  prep<<<8192 + 3072, 256, 0, stream>>>(mask, x, wq_w, wk_w, wv_w, dw,
                                        mb, xb, wcat, dwb);

  qkv_gemm<<<dim3(12, 64), 256, 0, stream>>>(xb, wcat, wq_b, wk_b, wv_b,
                                             Qb, Kb, V4);

  attn_mfma<<<1024, 256, 0, stream>>>(Qb, Kb, V4, mb, Opart, Lp);
  attn_merge<<<1024, 256, 0, stream>>>(Opart, Lp, Qb);

  dense_gemm<<<dim3(8, 128), 256, 0, stream>>>(Qb, dwb, db, (float*)d_out);
}

// Round 17
// 194.622 us; speedup vs baseline: 1.0039x; 1.0039x over previous
//
#include <hip/hip_runtime.h>
#include <hip/hip_bf16.h>

#define S_LEN 4096
#define DM    512
#define NH    8
#define DK    64

typedef __attribute__((ext_vector_type(8))) __bf16 bf16x8;
typedef __attribute__((ext_vector_type(4))) float  f32x4;
typedef unsigned short u16;
typedef unsigned int   u32;
typedef unsigned long long u64;

// Q-GEMM epilogue scale: 1/sqrt(64) * log2(e)  (softmax in log2 domain)
#define SQ_SCALE (0.125f * 1.44269504f)
// Fixed softmax shift (log2-domain). Shift-invariant; l-division restores scale.
#define FMAX 12.0f

// Split-K over the key axis: 4 partials of 1024 keys each.
#define NPART 4
#define KSPAN 1024

__device__ __forceinline__ u16 f2bf(float f) {
  union { float f; u32 i; } v; v.f = f;
  u32 r = v.i + 0x7fff + ((v.i >> 16) & 1);   // RNE
  return (u16)(r >> 16);
}
__device__ __forceinline__ float bf2f(u16 u) {
  union { u32 i; float f; } v; v.i = ((u32)u) << 16; return v.f;
}

// pack two f32 -> one u32 of 2 bf16 (RNE), single instruction; lo16=a, hi16=b.
// Verified correct in R8/R14/R15. NOTE (R9/R16 lesson): attn_mfma is
// schedule-fragile -- two semantically-safe source perturbations of its loop
// (mask-fold, setprio) produced corrupted output on recompilation while this
// exact build passed twice. The kernel is FROZEN at the R15-verified source.
__device__ __forceinline__ u32 cvtpk(float a, float b) {
  u32 r;
  asm("v_cvt_pk_bf16_f32 %0, %1, %2" : "=v"(r) : "v"(a), "v"(b));
  return r;
}

// async global->LDS DMA, 16B per lane (dest: wave-uniform base + lane*16)
__device__ __forceinline__ void gl_lds16(const u16* g, u16* l) {
  __builtin_amdgcn_global_load_lds(
      (const __attribute__((address_space(1))) u32*)g,
      (__attribute__((address_space(3))) u32*)l, 16, 0, 0);
}

// ---------------------------------------------------------------------------
// prep: fused mask-pack + fp32->bf16 conversion (R14-verified).
__global__ __launch_bounds__(256) void prep(
    const int* __restrict__ mask, const float* __restrict__ x,
    const float* __restrict__ wq, const float* __restrict__ wk,
    const float* __restrict__ wv, const float* __restrict__ dw,
    u64* __restrict__ mb, u16* __restrict__ xb, u16* __restrict__ wcat,
    u16* __restrict__ dwb) {
  const int b = blockIdx.x, t = threadIdx.x;
  if (b < 8192) {
    const int lane = t & 63, w4 = t >> 6;
    const int wb = b * 32 + w4 * 8;
    u64 bw[8];
#pragma unroll
    for (int j = 0; j < 8; j++)
      bw[j] = __ballot(mask[(size_t)(wb + j) * 64 + lane] != 0);
    if (lane == 0) {
#pragma unroll
      for (int j = 0; j < 8; j++) mb[wb + j] = bw[j];
    }
  } else {
    const int c = b - 8192;
    const float* src; u16* dst; size_t off;
    if      (c < 2048) { src = x;  dst = xb;   off = (size_t)c * 1024; }
    else if (c < 2304) { src = wq; dst = wcat; off = (size_t)(c - 2048) * 1024; }
    else if (c < 2560) { src = wk; dst = wcat + 262144; off = (size_t)(c - 2304) * 1024; }
    else if (c < 2816) { src = wv; dst = wcat + 524288; off = (size_t)(c - 2560) * 1024; }
    else               { src = dw; dst = dwb;  off = (size_t)(c - 2816) * 1024; }
    size_t i = off + (size_t)t * 4;
    float4 v = *reinterpret_cast<const float4*>(src + i);
    ushort4 o = make_ushort4(f2bf(v.x), f2bf(v.y), f2bf(v.z), f2bf(v.w));
    *reinterpret_cast<ushort4*>(dst + i) = o;
  }
}

// ---------------------------------------------------------------------------
// Fused QKV projection, 64(m) x 128(n) tiles: C[4096,1536] = x @ Wcat^T + bias.
// grid (12, 64). seg 0=Q (scaled), 1=K, 2=V.  (R7/R14-verified)
// V output layout V4[(h*64+d)][tile*64 + slot] (see attn_mfma).
__global__ __launch_bounds__(256) void qkv_gemm(
    const u16* __restrict__ A, const u16* __restrict__ Wcat,
    const float* __restrict__ bq, const float* __restrict__ bk,
    const float* __restrict__ bv,
    u16* __restrict__ Qb, u16* __restrict__ Kb, u16* __restrict__ V4) {
  __shared__ u16 As[2][64 * 64];    // 16 KB
  __shared__ u16 Ws[2][128 * 64];   // 32 KB (region reused as T in V epilogue)
  const int t = threadIdx.x;
  const int lane = t & 63, wv = t >> 6;
  const int m16 = lane & 15, quad = lane >> 4;
  const int n0g = blockIdx.x * 128, m0 = blockIdx.y * 64;
  const int seg = n0g >> 9;
  const int n0 = n0g & 511;
  const int mq = wv >> 1, nq = wv & 1;   // wave quadrant

  const u16* asrc[2]; int ldsoA[2];
#pragma unroll
  for (int c0 = 0; c0 < 2; c0++) {
    int c = t + c0 * 256;
    int row = c >> 3, swc = ((c & 7) ^ (row & 7)) * 8;
    asrc[c0] = A + (size_t)(m0 + row) * DM + swc;
    ldsoA[c0] = c * 8;
  }
  const u16* wsrc[4]; int ldsoW[4];
#pragma unroll
  for (int c0 = 0; c0 < 4; c0++) {
    int c = t + c0 * 256;
    int row = c >> 3, swc = ((c & 7) ^ (row & 7)) * 8;
    wsrc[c0] = Wcat + (size_t)(n0g + row) * DM + swc;
    ldsoW[c0] = c * 8;
  }

  f32x4 acc[2][4];
#pragma unroll
  for (int i = 0; i < 2; i++)
#pragma unroll
    for (int j = 0; j < 4; j++) acc[i][j] = (f32x4)0.f;

#pragma unroll
  for (int c0 = 0; c0 < 2; c0++) gl_lds16(asrc[c0], &As[0][ldsoA[c0]]);
#pragma unroll
  for (int c0 = 0; c0 < 4; c0++) gl_lds16(wsrc[c0], &Ws[0][ldsoW[c0]]);
  __syncthreads();

  const int xorv = m16 & 7;   // read-side granule swizzle
  int cur = 0;
  for (int k0 = 0; k0 < DM; k0 += 64) {
    if (k0 + 64 < DM) {
#pragma unroll
      for (int c0 = 0; c0 < 2; c0++)
        gl_lds16(asrc[c0] + k0 + 64, &As[cur ^ 1][ldsoA[c0]]);
#pragma unroll
      for (int c0 = 0; c0 < 4; c0++)
        gl_lds16(wsrc[c0] + k0 + 64, &Ws[cur ^ 1][ldsoW[c0]]);
    }
    const u16* Ac = As[cur];
    const u16* Wc = Ws[cur];
#pragma unroll
    for (int kk = 0; kk < 64; kk += 32) {
      const int gcol = (((quad + (kk >> 3)) ^ xorv) * 8);
      bf16x8 a0 = *reinterpret_cast<const bf16x8*>(&Ac[(mq * 32 + m16) * 64 + gcol]);
      bf16x8 a1 = *reinterpret_cast<const bf16x8*>(&Ac[(mq * 32 + 16 + m16) * 64 + gcol]);
#pragma unroll
      for (int ct = 0; ct < 4; ct++) {
        bf16x8 b = *reinterpret_cast<const bf16x8*>(&Wc[(nq * 64 + ct * 16 + m16) * 64 + gcol]);
        acc[0][ct] = __builtin_amdgcn_mfma_f32_16x16x32_bf16(a0, b, acc[0][ct], 0, 0, 0);
        acc[1][ct] = __builtin_amdgcn_mfma_f32_16x16x32_bf16(a1, b, acc[1][ct], 0, 0, 0);
      }
    }
    __syncthreads();
    cur ^= 1;
  }

  const float* bias = (seg == 0) ? bq : (seg == 1) ? bk : bv;
  const float scale = (seg == 0) ? SQ_SCALE : 1.f;
  float bn[4];
#pragma unroll
  for (int ct = 0; ct < 4; ct++) bn[ct] = bias[n0 + nq * 64 + ct * 16 + m16];

  if (seg == 2) {
    u16* T = &Ws[0][0];   // 9216 u16 needed <= 16384 available
#pragma unroll
    for (int rt = 0; rt < 2; rt++)
#pragma unroll
      for (int ct = 0; ct < 4; ct++)
#pragma unroll
        for (int r = 0; r < 4; r++)
          T[(nq * 64 + ct * 16 + m16) * 72 + mq * 32 + rt * 16 + quad * 4 + r] =
              f2bf(acc[rt][ct][r] + bn[ct]);
    __syncthreads();
    const int h    = m0 >> 9;
    const int mp   = m0 & 511;
    const int cseg = n0 >> 7;
#pragma unroll
    for (int c0 = 0; c0 < 4; c0++) {
      int c = t + c0 * 256;
      int d  = c >> 4;
      int tl = (c >> 1) & 7;
      int cl = c & 1;
      uint4 v = *reinterpret_cast<const uint4*>(&T[(cl * 64 + d) * 72 + tl * 8]);
      *reinterpret_cast<uint4*>(
          &V4[(size_t)(h * 64 + d) * 4096 + ((mp >> 3) + tl) * 64 + cl * 32 + cseg * 8]) = v;
    }
  } else {
    u16* dst = (seg == 0) ? Qb : Kb;
#pragma unroll
    for (int rt = 0; rt < 2; rt++)
#pragma unroll
      for (int ct = 0; ct < 4; ct++) {
        int n = n0 + nq * 64 + ct * 16 + m16;
#pragma unroll
        for (int r = 0; r < 4; r++) {
          int m = m0 + mq * 32 + rt * 16 + quad * 4 + r;
          dst[(size_t)m * DM + n] = f2bf((acc[rt][ct][r] + bn[ct]) * scale);
        }
      }
  }
}

// ---------------------------------------------------------------------------
// Dense out-proj (R15-verified): m-tile 32, grid (8, 128) = 4 blocks/CU.
// C[4096,512](f32) = A @ dw^T + db.
__global__ __launch_bounds__(256) void dense_gemm(
    const u16* __restrict__ A, const u16* __restrict__ W,
    const float* __restrict__ bias, float* __restrict__ Cout) {
  __shared__ u16 As[2][32 * 64];   // 4 KB each
  __shared__ u16 Ws[2][64 * 64];   // 8 KB each
  const int t = threadIdx.x;
  const int lane = t & 63, wv = t >> 6;
  const int m16 = lane & 15, quad = lane >> 4;
  const int n0 = blockIdx.x * 64, m0 = blockIdx.y * 32;
  const int mq = wv >> 1, nq = wv & 1;   // wave quadrant

  const u16* asrc; int ldsoA;
  {
    int c = t;
    int row = c >> 3, swc = ((c & 7) ^ (row & 7)) * 8;
    asrc = A + (size_t)(m0 + row) * DM + swc;
    ldsoA = c * 8;
  }
  const u16* wsrc[2]; int ldsoW[2];
#pragma unroll
  for (int c0 = 0; c0 < 2; c0++) {
    int c = t + c0 * 256;
    int row = c >> 3, swc = ((c & 7) ^ (row & 7)) * 8;
    wsrc[c0] = W + (size_t)(n0 + row) * DM + swc;
    ldsoW[c0] = c * 8;
  }

  f32x4 acc[2];
#pragma unroll
  for (int j = 0; j < 2; j++) acc[j] = (f32x4)0.f;

  gl_lds16(asrc, &As[0][ldsoA]);
#pragma unroll
  for (int c0 = 0; c0 < 2; c0++) gl_lds16(wsrc[c0], &Ws[0][ldsoW[c0]]);
  __syncthreads();

  const int xorv = m16 & 7;
  int cur = 0;
  for (int k0 = 0; k0 < DM; k0 += 64) {
    if (k0 + 64 < DM) {
      gl_lds16(asrc + k0 + 64, &As[cur ^ 1][ldsoA]);
#pragma unroll
      for (int c0 = 0; c0 < 2; c0++)
        gl_lds16(wsrc[c0] + k0 + 64, &Ws[cur ^ 1][ldsoW[c0]]);
    }
    const u16* Ac = As[cur];
    const u16* Wc = Ws[cur];
#pragma unroll
    for (int kk = 0; kk < 64; kk += 32) {
      const int gcol = (((quad + (kk >> 3)) ^ xorv) * 8);
      bf16x8 a = *reinterpret_cast<const bf16x8*>(&Ac[(mq * 16 + m16) * 64 + gcol]);
#pragma unroll
      for (int ct = 0; ct < 2; ct++) {
        bf16x8 b = *reinterpret_cast<const bf16x8*>(&Wc[(nq * 32 + ct * 16 + m16) * 64 + gcol]);
        acc[ct] = __builtin_amdgcn_mfma_f32_16x16x32_bf16(a, b, acc[ct], 0, 0, 0);
      }
    }
    __syncthreads();
    cur ^= 1;
  }

  float bn[2];
#pragma unroll
  for (int ct = 0; ct < 2; ct++) bn[ct] = bias[n0 + nq * 32 + ct * 16 + m16];
#pragma unroll
  for (int ct = 0; ct < 2; ct++) {
    int n = n0 + nq * 32 + ct * 16 + m16;
#pragma unroll
    for (int r = 0; r < 4; r++) {
      int m = m0 + mq * 16 + quad * 4 + r;
      Cout[(size_t)m * DM + n] = acc[ct][r] + bn[ct];
    }
  }
}

// ---------------------------------------------------------------------------
// exp2 + mask + pack one q-subtile's scores into the two PV A-fragments.
// Mask bit for C slot (ct,r): true key = 32(ct&1) + 16(r>>1) + 8(r&1)
// + 2*quad + (ct>>1); lo/hi are the lane's mask word pre-shifted by 2*quad.
// cvt_pk packing (R14/R15-verified).
__device__ __forceinline__ void pack_p(const f32x4* s, u32 lo, u32 hi,
                                       uint4& o0, uint4& o1) {
  u32 pk[8];
#pragma unroll
  for (int ct = 0; ct < 4; ct++) {
    u32 w = (ct & 1) ? hi : lo;
    int b = ct >> 1;
    float p0 = __builtin_amdgcn_exp2f(((w >> b) & 1u)        ? -1e9f : s[ct][0]);
    float p1 = __builtin_amdgcn_exp2f(((w >> (b + 8)) & 1u)  ? -1e9f : s[ct][1]);
    float p2 = __builtin_amdgcn_exp2f(((w >> (b + 16)) & 1u) ? -1e9f : s[ct][2]);
    float p3 = __builtin_amdgcn_exp2f(((w >> (b + 24)) & 1u) ? -1e9f : s[ct][3]);
    pk[2 * ct]     = cvtpk(p0, p1);
    pk[2 * ct + 1] = cvtpk(p2, p3);
  }
  o0 = make_uint4(pk[0], pk[1], pk[2], pk[3]);
  o1 = make_uint4(pk[4], pk[5], pk[6], pk[7]);
}

// ---------------------------------------------------------------------------
// Flash attention v6 (R14/R15-verified, 57.5 us; FROZEN -- see cvtpk note):
// LDS double-buffer filled by global_load_lds DMA, 1 barrier/iter,
// sigma^{-1}-pre-permuted K source rows, bank-XOR involution (0 conflicts).
// S^T C-layout registers exp2'd + cvt_pk-packed ARE the PV A-fragments.
// Grid 1D 1024, lin&7 = (h,g) group -> XCD-local K/V.
__global__ __launch_bounds__(256, 4) void attn_mfma(
    const u16* __restrict__ Q, const u16* __restrict__ K,
    const u16* __restrict__ V4, const u64* __restrict__ mbits,
    u16* __restrict__ Op, float* __restrict__ Lp) {
  __shared__ u16 Ks[2][64 * 64];   // 8 KB each
  __shared__ u16 Vs[2][64 * 64];

  const int t = threadIdx.x;
  const int lane = t & 63, w4 = t >> 6;
  const int m16 = lane & 15, quad = lane >> 4;
  const int lin = blockIdx.x;
  const int q0 = ((lin >> 3) & 31) * 128;
  const int hg = ((lin >> 8) << 3) | (lin & 7);   // 0..31, lin&7 = XCD group
  const int h = hg & 7;
  const int g = hg >> 3;                          // key quarter: 1024 keys
  const size_t hoff = (size_t)h * S_LEN * DK;
  const size_t kbase = hoff + (size_t)g * KSPAN * DK;

  // Q fragments for the wave's two q-subtiles (pre-scaled in Q-GEMM)
  const u16* qpA = Q + hoff + (size_t)(q0 + w4 * 32 + m16) * DK + quad * 8;
  bf16x8 qloA = *reinterpret_cast<const bf16x8*>(qpA);
  bf16x8 qhiA = *reinterpret_cast<const bf16x8*>(qpA + 32);
  bf16x8 qloB = *reinterpret_cast<const bf16x8*>(qpA + 16 * DK);
  bf16x8 qhiB = *reinterpret_cast<const bf16x8*>(qpA + 16 * DK + 32);

  union { u16 u[8]; bf16x8 v; } onesu;
#pragma unroll
  for (int j = 0; j < 8; j++) onesu.u[j] = 0x3F80;
  const bf16x8 ones = onesu.v;

  // DMA staging geometry (thread-constant); see R6 comments.
  const int l = lane;
  const int colu = ((l & 7) ^ (l >> 3)) * 8;      // u16 units
  const u16* kp[2]; const u16* vp[2]; int ldso[2];
#pragma unroll
  for (int i = 0; i < 2; i++) {
    int row = (w4 * 2 + i) * 8 + (l >> 3);
    int inv = (((row >> 4) & 1) << 5) | (((row >> 1) & 1) << 4) | ((row & 1) << 3) |
              (((row >> 3) & 1) << 2) | (((row >> 2) & 1) << 1) | ((row >> 5) & 1);
    kp[i] = K + kbase + (size_t)inv * DK + colu;
    vp[i] = V4 + (size_t)(h * 64 + row) * 4096 + g * KSPAN + colu;
    ldso[i] = (w4 * 2 + i) * 512 + l * 8;        // u16 units, 16B/lane
  }

  const u64* mpA = &mbits[(size_t)(q0 + w4 * 32 + m16) * 64 + ((g * KSPAN) >> 6)];
  const u64* mpB = mpA + (size_t)16 * 64;   // +16 q rows

  f32x4 accA[4], accB[4];
  f32x4 acc_lA = (f32x4)0.f, acc_lB = (f32x4)0.f;
#pragma unroll
  for (int dt = 0; dt < 4; dt++) { accA[dt] = (f32x4)0.f; accB[dt] = (f32x4)0.f; }

  // Prologue: DMA tile 0 into buf 0; mask words for tile 0 into regs.
#pragma unroll
  for (int i = 0; i < 2; i++) {
    gl_lds16(kp[i], &Ks[0][ldso[i]]);
    gl_lds16(vp[i], &Vs[0][ldso[i]]);
  }
  u64 rmA = mpA[0], rmB = mpB[0];
  __syncthreads();   // drains tile-0 DMA

  const int xorv = (m16 & 7) * 8;   // read-side swizzle (u16 units)
  int cur = 0;
#pragma unroll 1
  for (int k0 = 0; k0 < KSPAN; k0 += 64) {
    // Issue next tile's DMA first: latency hides under this tile's compute.
    if (k0 + 64 < KSPAN) {
#pragma unroll
      for (int i = 0; i < 2; i++) {
        gl_lds16(kp[i] + (size_t)(k0 + 64) * DK, &Ks[cur ^ 1][ldso[i]]);
        gl_lds16(vp[i] + (k0 + 64),              &Vs[cur ^ 1][ldso[i]]);
      }
    }
    u64 mqA = rmA >> (2 * quad);
    u64 mqB = rmB >> (2 * quad);
    if (k0 + 64 < KSPAN) { rmA = mpA[(k0 >> 6) + 1]; rmB = mpB[(k0 >> 6) + 1]; }

    const u16* Kc = Ks[cur];
    const u16* Vc = Vs[cur];

    // S^T - FMAX for both q-subtiles; each K fragment feeds 2 MFMAs
    f32x4 sA[4], sB[4];
#pragma unroll
    for (int ct = 0; ct < 4; ct++) { sA[ct] = (f32x4)(-FMAX); sB[ct] = (f32x4)(-FMAX); }
#pragma unroll
    for (int ct = 0; ct < 4; ct++) {
      const int rb = (ct * 16 + m16) * 64;
      bf16x8 klo = *reinterpret_cast<const bf16x8*>(&Kc[rb + ((quad * 8) ^ xorv)]);
      bf16x8 khi = *reinterpret_cast<const bf16x8*>(&Kc[rb + ((quad * 8 + 32) ^ xorv)]);
      sA[ct] = __builtin_amdgcn_mfma_f32_16x16x32_bf16(klo, qloA, sA[ct], 0, 0, 0);
      sA[ct] = __builtin_amdgcn_mfma_f32_16x16x32_bf16(khi, qhiA, sA[ct], 0, 0, 0);
      sB[ct] = __builtin_amdgcn_mfma_f32_16x16x32_bf16(klo, qloB, sB[ct], 0, 0, 0);
      sB[ct] = __builtin_amdgcn_mfma_f32_16x16x32_bf16(khi, qhiB, sB[ct], 0, 0, 0);
    }

    // exp2 + pack: registers become the PV A-fragments directly (no LDS)
    union { uint4 i; bf16x8 v; } pA0, pA1, pB0, pB1;
    pack_p(sA, (u32)mqA, (u32)(mqA >> 32), pA0.i, pA1.i);
    pack_p(sB, (u32)mqB, (u32)(mqB >> 32), pB0.i, pB1.i);

    // O += P @ V ; l += P @ 1; each V fragment feeds 2 MFMAs
#pragma unroll
    for (int dt = 0; dt < 4; dt++) {
      const int rb = (dt * 16 + m16) * 64;
      bf16x8 vlo = *reinterpret_cast<const bf16x8*>(&Vc[rb + ((quad * 8) ^ xorv)]);
      bf16x8 vhi = *reinterpret_cast<const bf16x8*>(&Vc[rb + ((quad * 8 + 32) ^ xorv)]);
      accA[dt] = __builtin_amdgcn_mfma_f32_16x16x32_bf16(pA0.v, vlo, accA[dt], 0, 0, 0);
      accA[dt] = __builtin_amdgcn_mfma_f32_16x16x32_bf16(pA1.v, vhi, accA[dt], 0, 0, 0);
      accB[dt] = __builtin_amdgcn_mfma_f32_16x16x32_bf16(pB0.v, vlo, accB[dt], 0, 0, 0);
      accB[dt] = __builtin_amdgcn_mfma_f32_16x16x32_bf16(pB1.v, vhi, accB[dt], 0, 0, 0);
    }
    acc_lA = __builtin_amdgcn_mfma_f32_16x16x32_bf16(pA0.v, ones, acc_lA, 0, 0, 0);
    acc_lA = __builtin_amdgcn_mfma_f32_16x16x32_bf16(pA1.v, ones, acc_lA, 0, 0, 0);
    acc_lB = __builtin_amdgcn_mfma_f32_16x16x32_bf16(pB0.v, ones, acc_lB, 0, 0, 0);
    acc_lB = __builtin_amdgcn_mfma_f32_16x16x32_bf16(pB1.v, ones, acc_lB, 0, 0, 0);

    __syncthreads();   // sync + drain next-tile DMA (hidden under compute)
    cur ^= 1;
  }

  // partial O (unnormalized bf16) + partial l (f32)
  u16* Og = Op + (size_t)g * 2097152;
#pragma unroll
  for (int dt = 0; dt < 4; dt++)
#pragma unroll
    for (int r = 0; r < 4; r++) {
      Og[(size_t)(q0 + w4 * 32 + quad * 4 + r) * DM + h * DK + dt * 16 + m16] =
          f2bf(accA[dt][r]);
      Og[(size_t)(q0 + w4 * 32 + 16 + quad * 4 + r) * DM + h * DK + dt * 16 + m16] =
          f2bf(accB[dt][r]);
    }
  if (m16 == 0) {
#pragma unroll
    for (int r = 0; r < 4; r++) {
      Lp[g * 32768 + h * 4096 + q0 + w4 * 32 + quad * 4 + r] = acc_lA[r];
      Lp[g * 32768 + h * 4096 + q0 + w4 * 32 + 16 + quad * 4 + r] = acc_lB[r];
    }
  }
}

// ---------------------------------------------------------------------------
// Merge the four key-quarter partials: Out = sum(O_g) / sum(l_g). bf16 out.
__global__ __launch_bounds__(256) void attn_merge(
    const u16* __restrict__ Op, const float* __restrict__ Lp,
    u16* __restrict__ Out) {
  int i8 = (blockIdx.x * 256 + threadIdx.x) * 8;   // 8 elems/thread, same (q,h)
  int q = i8 >> 9;
  int h = (i8 >> 6) & 7;
  float l = 0.f;
#pragma unroll
  for (int part = 0; part < NPART; part++) l += Lp[part * 32768 + h * 4096 + q];
  float rl = 1.f / l;
  float o[8];
#pragma unroll
  for (int j = 0; j < 8; j++) o[j] = 0.f;
#pragma unroll
  for (int part = 0; part < NPART; part++) {
    ushort4 v0 = *reinterpret_cast<const ushort4*>(Op + (size_t)part * 2097152 + i8);
    ushort4 v1 = *reinterpret_cast<const ushort4*>(Op + (size_t)part * 2097152 + i8 + 4);
    o[0] += bf2f(v0.x); o[1] += bf2f(v0.y); o[2] += bf2f(v0.z); o[3] += bf2f(v0.w);
    o[4] += bf2f(v1.x); o[5] += bf2f(v1.y); o[6] += bf2f(v1.z); o[7] += bf2f(v1.w);
  }
  ushort4 o0 = make_ushort4(f2bf(o[0] * rl), f2bf(o[1] * rl),
                            f2bf(o[2] * rl), f2bf(o[3] * rl));
  ushort4 o1 = make_ushort4(f2bf(o[4] * rl), f2bf(o[5] * rl),
                            f2bf(o[6] * rl), f2bf(o[7] * rl));
  *reinterpret_cast<ushort4*>(Out + i8) = o0;
  *reinterpret_cast<ushort4*>(Out + i8 + 4) = o1;
}

// ---------------------------------------------------------------------------
extern "C" void kernel_launch(void* const* d_in, const int* in_sizes, int n_in,
                              void* d_out, int out_size, void* d_ws, size_t ws_size,
                              hipStream_t stream) {
  const float* x    = (const float*)d_in[0];
  const int*   mask = (const int*)d_in[1];
  const float* wq_w = (const float*)d_in[2];
  const float* wq_b = (const float*)d_in[3];
  const float* wk_w = (const float*)d_in[4];
  const float* wk_b = (const float*)d_in[5];
  const float* wv_w = (const float*)d_in[6];
  const float* wv_b = (const float*)d_in[7];
  const float* dw   = (const float*)d_in[8];
  const float* db   = (const float*)d_in[9];

  // ws (u16 elems): xb 2M | wcat 768K | dwb 256K | Qb/Kb/V4 2M each |
  // Opart 4x2M | mb 256K u64 | Lp 128K f32.  ~37 MB total.
  u16* xb    = (u16*)d_ws;
  u16* wcat  = xb    + 2097152;
  u16* dwb   = wcat  + 786432;
  u16* Qb    = dwb   + 262144;
  u16* Kb    = Qb    + 2097152;
  u16* V4    = Kb    + 2097152;
  u16* Opart = V4    + 2097152;
  u64* mb    = (u64*)(Opart + (size_t)NPART * 2097152);
  float* Lp  = (float*)(mb + 262144);

  prep<<<8192 + 3072, 256, 0, stream>>>(mask, x, wq_w, wk_w, wv_w, dw,
                                        mb, xb, wcat, dwb);

  qkv_gemm<<<dim3(12, 64), 256, 0, stream>>>(xb, wcat, wq_b, wk_b, wv_b,
                                             Qb, Kb, V4);

  attn_mfma<<<1024, 256, 0, stream>>>(Qb, Kb, V4, mb, Opart, Lp);
  attn_merge<<<1024, 256, 0, stream>>>(Opart, Lp, Qb);

  dense_gemm<<<dim3(8, 128), 256, 0, stream>>>(Qb, dwb, db, (float*)d_out);
}